// Round 1
// baseline (829.055 us; speedup 1.0000x reference)
//
#include <hip/hip_runtime.h>

#define B_  32
#define C_  384
#define HW_ 784
#define N_  25088   // B_*HW_
#define K_  2048

#define OFF_F    0
#define OFF_Q    9633792
#define OFF_ASG  19267584
#define OFF_DIST 70647808

// ---------------- K1: normalize codebook rows ----------------
__global__ __launch_bounds__(256) void k_norm_code(const float* __restrict__ cb,
                                                   float* __restrict__ code_n) {
    int row  = blockIdx.x * 4 + (threadIdx.x >> 6);
    int lane = threadIdx.x & 63;
    const float* src = cb + (size_t)row * C_;
    float v[6];
    float ss = 0.f;
#pragma unroll
    for (int i = 0; i < 6; ++i) { v[i] = src[lane + 64 * i]; ss += v[i] * v[i]; }
#pragma unroll
    for (int off = 32; off; off >>= 1) ss += __shfl_xor(ss, off, 64);
    float inv = 1.f / fmaxf(sqrtf(ss), 1e-12f);
    float* dst = code_n + (size_t)row * C_;
#pragma unroll
    for (int i = 0; i < 6; ++i) dst[lane + 64 * i] = v[i] * inv;
}

// ---------------- K2: transpose feat -> f, and normalized flat_n ----------------
// one block (384 threads) per pixel
__global__ __launch_bounds__(384) void k_transpose_norm(const float* __restrict__ feat,
                                                        float* __restrict__ f_out,
                                                        float* __restrict__ flat_n) {
    int n  = blockIdx.x;
    int b  = n / HW_;
    int hw = n - b * HW_;
    int c  = threadIdx.x;
    float v = feat[((size_t)b * C_ + c) * HW_ + hw];
    __shared__ float red[384];
    red[c] = v * v;
    __syncthreads();
    if (c < 128) red[c] += red[c + 128] + red[c + 256];
    __syncthreads();
    if (c < 64) red[c] += red[c + 64];
    __syncthreads();
    if (c < 64) {
        float ss = red[c];
#pragma unroll
        for (int off = 32; off; off >>= 1) ss += __shfl_xor(ss, off, 64);
        if (c == 0) red[0] = ss;
    }
    __syncthreads();
    float inv = 1.f / fmaxf(sqrtf(red[0]), 1e-12f);
    f_out [(size_t)n * C_ + c] = v;
    flat_n[(size_t)n * C_ + c] = v * inv;
}

// ---------------- K3: fp32 GEMM, distance = 2 - 2 * A.B^T ----------------
// A: N_ x C_ (flat_n), Bm: K_ x C_ (code_n), D: N_ x K_
#define TM 64
#define TN 64
#define TK 16
__global__ __launch_bounds__(256) void k_gemm(const float* __restrict__ A,
                                              const float* __restrict__ Bm,
                                              float* __restrict__ D) {
    __shared__ float As[TK][TM];
    __shared__ float Bs[TK][TN];
    int tid = threadIdx.x;
    int m0 = blockIdx.x * TM;
    int n0 = blockIdx.y * TN;
    int tx = tid & 15, ty = tid >> 4;          // 16x16 threads, 4x4 micro-tile
    int lr = tid >> 2, lc = (tid & 3) * 4;     // loader: row, col(float4)
    float acc[4][4] = {};
    for (int c0 = 0; c0 < C_; c0 += TK) {
        float4 av = *(const float4*)(A  + (size_t)(m0 + lr) * C_ + c0 + lc);
        float4 bv = *(const float4*)(Bm + (size_t)(n0 + lr) * C_ + c0 + lc);
        __syncthreads();
        As[lc + 0][lr] = av.x; As[lc + 1][lr] = av.y; As[lc + 2][lr] = av.z; As[lc + 3][lr] = av.w;
        Bs[lc + 0][lr] = bv.x; Bs[lc + 1][lr] = bv.y; Bs[lc + 2][lr] = bv.z; Bs[lc + 3][lr] = bv.w;
        __syncthreads();
#pragma unroll
        for (int kk = 0; kk < TK; ++kk) {
            float a[4], b[4];
#pragma unroll
            for (int i = 0; i < 4; ++i) a[i] = As[kk][ty * 4 + i];
#pragma unroll
            for (int j = 0; j < 4; ++j) b[j] = Bs[kk][tx * 4 + j];
#pragma unroll
            for (int i = 0; i < 4; ++i)
#pragma unroll
                for (int j = 0; j < 4; ++j) acc[i][j] = fmaf(a[i], b[j], acc[i][j]);
        }
    }
#pragma unroll
    for (int i = 0; i < 4; ++i) {
        int m = m0 + ty * 4 + i;
        float4 o;
        o.x = 2.f - 2.f * acc[i][0];
        o.y = 2.f - 2.f * acc[i][1];
        o.z = 2.f - 2.f * acc[i][2];
        o.w = 2.f - 2.f * acc[i][3];
        *(float4*)(D + (size_t)m * K_ + n0 + tx * 4) = o;
    }
}

// ---------------- K4: per-row softmax-sum, argmin, q gather, assignment write ----------------
// 8 pixels per block (784 % 8 == 0, so tiles never straddle a batch)
__global__ __launch_bounds__(256) void k_rowpost(const float* __restrict__ D,
                                                 const float* __restrict__ code_n,
                                                 float* __restrict__ asg,
                                                 float* __restrict__ q_out) {
    __shared__ float buf[8][256];   // XOR-swizzled staging for transposed writes
    __shared__ float s_inv[8];
    __shared__ int   s_amin[8];
    int n0  = blockIdx.x * 8;
    int b   = n0 / HW_;
    int hw0 = n0 - b * HW_;
    int tid = threadIdx.x;
    int r = tid >> 5, j = tid & 31;            // 8 rows x 32 threads

    const float* drow = D + (size_t)(n0 + r) * K_;
    float lsum = 0.f, dmin = 3.4e38f;
    int   kmin = 0;
#pragma unroll 4
    for (int i = 0; i < K_ / 32; ++i) {
        int k = j + 32 * i;
        float d = drow[k];
        lsum += __expf(-10.f * d);
        if (d < dmin) { dmin = d; kmin = k; }  // k increasing within thread -> first-index kept
    }
#pragma unroll
    for (int off = 16; off; off >>= 1) {
        float od = __shfl_xor(dmin, off, 32);
        int   ok = __shfl_xor(kmin, off, 32);
        lsum += __shfl_xor(lsum, off, 32);
        if (od < dmin || (od == dmin && ok < kmin)) { dmin = od; kmin = ok; }
    }
    if (j == 0) { s_inv[r] = 1.f / lsum; s_amin[r] = kmin; }
    __syncthreads();

    int   rr  = tid & 7;
    int   cb0 = tid >> 3;                      // 0..31
    // q gather: q_out[b][c][hw0+rr] = code_n[amin][c]
    {
        int km = s_amin[rr];
        for (int c = cb0; c < C_; c += 32)
            q_out[((size_t)b * C_ + c) * HW_ + hw0 + rr] = code_n[(size_t)km * C_ + c];
    }
    // assignment: asg[b][k][hw0+rr] = exp(-10 d)/sum, staged through LDS per 256-k chunk
    float inv = s_inv[rr];
    for (int ch = 0; ch < K_ / 256; ++ch) {
        int k0 = ch * 256;
        __syncthreads();
#pragma unroll
        for (int i = 0; i < 8; ++i) {
            int kk = j + 32 * i;
            float d = drow[k0 + kk];
            buf[r][kk ^ (r << 2)] = __expf(-10.f * d);
        }
        __syncthreads();
#pragma unroll
        for (int i = 0; i < 8; ++i) {
            int kk = cb0 + 32 * i;
            float e = buf[rr][kk ^ (rr << 2)];
            asg[((size_t)b * K_ + (k0 + kk)) * HW_ + hw0 + rr] = e * inv;
        }
    }
}

extern "C" void kernel_launch(void* const* d_in, const int* in_sizes, int n_in,
                              void* d_out, int out_size, void* d_ws, size_t ws_size,
                              hipStream_t stream) {
    const float* feat = (const float*)d_in[0];
    const float* cb   = (const float*)d_in[1];
    float* out    = (float*)d_out;
    float* f_out  = out + OFF_F;
    float* q_out  = out + OFF_Q;
    float* asg    = out + OFF_ASG;
    float* dist   = out + OFF_DIST;
    float* code_n = (float*)d_ws;          // 2048*384 floats = 3.1 MB
    float* flat_n = asg;                   // borrow assignment region until K4 rewrites it

    k_norm_code<<<K_ / 4, 256, 0, stream>>>(cb, code_n);
    k_transpose_norm<<<N_, 384, 0, stream>>>(feat, f_out, flat_n);
    dim3 g3(N_ / TM, K_ / TN);
    k_gemm<<<g3, 256, 0, stream>>>(flat_n, code_n, dist);
    k_rowpost<<<N_ / 8, 256, 0, stream>>>(dist, code_n, asg, q_out);
}

// Round 2
// 303.610 us; speedup vs baseline: 2.7307x; 2.7307x over previous
//
#include <hip/hip_runtime.h>

#define B_  32
#define C_  384
#define HW_ 784
#define N_  25088   // B_*HW_
#define K_  2048

#define OFF_F    0
#define OFF_Q    9633792
#define OFF_ASG  19267584
#define OFF_DIST 70647808

#define MARGIN 6e-3f

typedef unsigned short u16;
typedef __attribute__((ext_vector_type(8))) short short8;
typedef __attribute__((ext_vector_type(4))) float floatx4;

static __device__ __forceinline__ u16 f2bf(float x) {
    unsigned u = __builtin_bit_cast(unsigned, x);
    unsigned r = (u + 0x7FFFu + ((u >> 16) & 1u)) >> 16;
    return (u16)r;
}

static __device__ __forceinline__ void gload_lds16(const void* g, void* l) {
    __builtin_amdgcn_global_load_lds(
        (const __attribute__((address_space(1))) unsigned int*)g,
        (__attribute__((address_space(3))) unsigned int*)l,
        16, 0, 0);
}

// ---------------- K1: normalize codebook -> code_n (fp32, ws) + b_hi (bf16) ----------------
__global__ __launch_bounds__(256) void k_code(const float* __restrict__ cb,
                                              float* __restrict__ code_n,
                                              u16* __restrict__ b_hi) {
    int row  = blockIdx.x * 4 + (threadIdx.x >> 6);
    int lane = threadIdx.x & 63;
    const float* src = cb + (size_t)row * C_;
    float v[6];
    float ss = 0.f;
#pragma unroll
    for (int i = 0; i < 6; ++i) { v[i] = src[lane + 64 * i]; ss += v[i] * v[i]; }
#pragma unroll
    for (int off = 32; off; off >>= 1) ss += __shfl_xor(ss, off, 64);
    float inv = 1.f / fmaxf(sqrtf(ss), 1e-12f);
#pragma unroll
    for (int i = 0; i < 6; ++i) {
        float vn = v[i] * inv;
        code_n[(size_t)row * C_ + lane + 64 * i] = vn;
        b_hi  [(size_t)row * C_ + lane + 64 * i] = f2bf(vn);
    }
}

// ---------------- K2: feat -> f (NC), flat_n (fp32 CHW, q region), a_hi (bf16 NC) ----------------
// block = (hw tile of 16, batch b); 256 threads
__global__ __launch_bounds__(256) void k_prep(const float* __restrict__ feat,
                                              float* __restrict__ f_out,
                                              float* flatn,
                                              u16* __restrict__ a_hi) {
    __shared__ float tile[C_][17];
    __shared__ float red[16][17];
    __shared__ float s_inv[16];
    int b   = blockIdx.y;
    int hw0 = blockIdx.x * 16;
    int tid = threadIdx.x;
    int px  = tid & 15, cq = tid >> 4;

    // coalesced load: 16 consecutive hw per c-row
#pragma unroll
    for (int it = 0; it < 24; ++it) {
        int c = cq + 16 * it;
        tile[c][px] = feat[((size_t)(b * C_ + c)) * HW_ + hw0 + px];
    }
    __syncthreads();
    // per-pixel sum of squares: 16 partials per pixel
    float ss = 0.f;
#pragma unroll
    for (int q = 0; q < 24; ++q) {
        float v = tile[cq + 16 * q][px];
        ss = fmaf(v, v, ss);
    }
    red[cq][px] = ss;
    __syncthreads();
    if (tid < 16) {
        float tot = 0.f;
#pragma unroll
        for (int p = 0; p < 16; ++p) tot += red[p][tid];
        s_inv[tid] = 1.f / fmaxf(sqrtf(tot), 1e-12f);
    }
    __syncthreads();

    // f (N,C layout): lanes over c
    {
        int p2 = tid >> 4, cc = tid & 15;
        size_t nbase = ((size_t)(b * HW_ + hw0 + p2)) * C_;
#pragma unroll
        for (int it = 0; it < 24; ++it) {
            int c = cc + 16 * it;
            f_out[nbase + c] = tile[c][p2];
        }
    }
    // flat_n (CHW layout, fp32): lanes over hw
    {
        float inv = s_inv[px];
#pragma unroll
        for (int it = 0; it < 24; ++it) {
            int c = cq + 16 * it;
            flatn[((size_t)(b * C_ + c)) * HW_ + hw0 + px] = tile[c][px] * inv;
        }
    }
    // a_hi (N,C layout, bf16, ushort2-packed): lanes over c
    {
        int p2 = tid >> 4, cc = tid & 15;
        float inv = s_inv[p2];
        size_t nbase = ((size_t)(b * HW_ + hw0 + p2)) * C_;
#pragma unroll
        for (int it = 0; it < 12; ++it) {
            int c0 = 2 * cc + 32 * it;
            u16 h0 = f2bf(tile[c0][p2] * inv);
            u16 h1 = f2bf(tile[c0 + 1][p2] * inv);
            unsigned pk = (unsigned)h0 | ((unsigned)h1 << 16);
            *(unsigned*)(a_hi + nbase + c0) = pk;
        }
    }
}

// ---------------- K3: bf16 MFMA GEMM, dist = 2 - 2 * A.B^T ----------------
// 128x128 tile, BK=32, double-buffered global_load_lds, pre-swizzled source
__global__ __launch_bounds__(256) void k_gemm(const u16* __restrict__ A,
                                              const u16* __restrict__ Bm,
                                              float* __restrict__ D) {
    __shared__ u16 As[2][128 * 32];
    __shared__ u16 Bs[2][128 * 32];
    int tid = threadIdx.x;
    int n0 = blockIdx.x * 128, m0 = blockIdx.y * 128;
    int w = tid >> 6, l = tid & 63;
    int wm = (w >> 1) * 64, wn = (w & 1) * 64;
    int q4 = l >> 4, r15 = l & 15;

    floatx4 acc[4][4];
#pragma unroll
    for (int i = 0; i < 4; ++i)
#pragma unroll
        for (int j = 0; j < 4; ++j) acc[i][j] = (floatx4)0.f;

    int srow = tid >> 2;            // 0..63 within a 256-lane round
    int sp   = tid & 3;             // 16B slot in 64B row
    int kk0  = 8 * (sp ^ (srow & 3));  // pre-swizzled global k-chunk

#define STAGE(buf, kt)                                                          \
    {                                                                           \
        _Pragma("unroll")                                                       \
        for (int q = 0; q < 2; ++q) {                                           \
            int row = q * 64 + srow;                                            \
            int off = (q * 256 + tid) * 16;                                     \
            gload_lds16(A  + (size_t)(m0 + row) * C_ + (kt) + kk0,              \
                        (char*)As[buf] + off);                                  \
            gload_lds16(Bm + (size_t)(n0 + row) * C_ + (kt) + kk0,              \
                        (char*)Bs[buf] + off);                                  \
        }                                                                       \
    }

    STAGE(0, 0);
    __syncthreads();

    int slot = (q4 ^ (r15 & 3)) << 4;   // swizzled 16B slot for this lane
#pragma unroll 1
    for (int t = 0; t < 12; ++t) {
        int cur = t & 1;
        if (t < 11) STAGE(cur ^ 1, (t + 1) * 32);
        const char* Ab = (const char*)As[cur];
        const char* Bb = (const char*)Bs[cur];
        short8 a[4], b[4];
#pragma unroll
        for (int i = 0; i < 4; ++i) {
            a[i] = *(const short8*)(Ab + (wm + i * 16 + r15) * 64 + slot);
            b[i] = *(const short8*)(Bb + (wn + i * 16 + r15) * 64 + slot);
        }
#pragma unroll
        for (int i = 0; i < 4; ++i)
#pragma unroll
            for (int j = 0; j < 4; ++j)
                acc[i][j] = __builtin_amdgcn_mfma_f32_16x16x32_bf16(a[i], b[j], acc[i][j], 0, 0, 0);
        __syncthreads();
    }

#pragma unroll
    for (int i = 0; i < 4; ++i) {
        int gm = m0 + wm + i * 16 + q4 * 4;
#pragma unroll
        for (int j = 0; j < 4; ++j) {
            int gn = n0 + wn + j * 16 + r15;
            float* p = D + (size_t)gm * K_ + gn;
#pragma unroll
            for (int r = 0; r < 4; ++r)
                p[(size_t)r * K_] = 2.f - 2.f * acc[i][j][r];
        }
    }
#undef STAGE
}

// ---------------- K4: softmax-sum, argmin(+exact recheck), assignment, q ----------------
// block = 16 pixels, 256 threads
__global__ __launch_bounds__(256) void k_post(const float* __restrict__ D,
                                              const float* __restrict__ code_n,
                                              const float* flatn,
                                              float* __restrict__ asg,
                                              float* q_out) {
    __shared__ float ebuf[16][260];
    __shared__ float s_dmin[16], s_inv[16];
    __shared__ int   s_amin[16], s_cnt[16], s_cand[16][32];
    int n0  = blockIdx.x * 16;
    int b   = n0 / HW_;
    int hw0 = n0 - b * HW_;
    int tid = threadIdx.x;
    int r = tid >> 4, j = tid & 15;
    const float* drow = D + (size_t)(n0 + r) * K_;
    if (j == 0) s_cnt[r] = 0;

    // pass 1: sum of exp, argmin
    float lsum = 0.f, dmin = 3.4e38f;
    int   kmin = 0;
#pragma unroll 4
    for (int i = 0; i < 32; ++i) {
        int k = 4 * j + 64 * i;
        float4 dv = *(const float4*)(drow + k);
        float d0 = dv.x, d1 = dv.y, d2 = dv.z, d3 = dv.w;
        lsum += __expf(-10.f * d0) + __expf(-10.f * d1)
              + __expf(-10.f * d2) + __expf(-10.f * d3);
        if (d0 < dmin) { dmin = d0; kmin = k; }
        if (d1 < dmin) { dmin = d1; kmin = k + 1; }
        if (d2 < dmin) { dmin = d2; kmin = k + 2; }
        if (d3 < dmin) { dmin = d3; kmin = k + 3; }
    }
#pragma unroll
    for (int off = 8; off; off >>= 1) {
        float od = __shfl_xor(dmin, off, 16);
        int   ok = __shfl_xor(kmin, off, 16);
        lsum += __shfl_xor(lsum, off, 16);
        if (od < dmin || (od == dmin && ok < kmin)) { dmin = od; kmin = ok; }
    }
    if (j == 0) { s_dmin[r] = dmin; s_inv[r] = 1.f / lsum; s_amin[r] = kmin; }
    __syncthreads();

    float inv = s_inv[r], dmn = s_dmin[r];
    // pass 2: assignment (transposed via LDS) + candidate collection
    for (int ch = 0; ch < 8; ++ch) {
        int k0 = ch * 256;
        __syncthreads();
#pragma unroll
        for (int i = 0; i < 4; ++i) {
            int kk = 4 * j + 64 * i;
            float4 dv = *(const float4*)(drow + k0 + kk);
            float dd[4] = {dv.x, dv.y, dv.z, dv.w};
#pragma unroll
            for (int c4 = 0; c4 < 4; ++c4) {
                float d = dd[c4];
                ebuf[r][kk + c4] = __expf(-10.f * d) * inv;
                if (d <= dmn + MARGIN) {
                    int idx = atomicAdd(&s_cnt[r], 1);
                    if (idx < 32) s_cand[r][idx] = k0 + kk + c4;
                }
            }
        }
        __syncthreads();
        int px2 = tid & 15, kt = tid >> 4;
#pragma unroll
        for (int w2 = 0; w2 < 16; ++w2) {
            int kk = kt + 16 * w2;
            asg[((size_t)(b * K_ + k0 + kk)) * HW_ + hw0 + px2] = ebuf[px2][kk];
        }
    }
    __syncthreads();

    // exact fp32 recheck for ambiguous pixels (reads flat_n before q overwrite)
    int w = tid >> 6, l = tid & 63;
    for (int t2 = 0; t2 < 4; ++t2) {
        int px  = w + 4 * t2;
        int cnt = s_cnt[px];
        if (cnt >= 2) {
            cnt = min(cnt, 32);
            float fv[6];
#pragma unroll
            for (int ii = 0; ii < 6; ++ii)
                fv[ii] = flatn[((size_t)(b * C_ + l + 64 * ii)) * HW_ + hw0 + px];
            float dbest = 3.4e38f;
            int   kbest = -1;
            for (int ci = 0; ci < cnt; ++ci) {
                int k = s_cand[px][ci];
                const float* cr = code_n + (size_t)k * C_;
                float dot = 0.f;
#pragma unroll
                for (int ii = 0; ii < 6; ++ii) dot = fmaf(fv[ii], cr[l + 64 * ii], dot);
#pragma unroll
                for (int off = 32; off; off >>= 1) dot += __shfl_xor(dot, off, 64);
                float dex = 2.f - 2.f * dot;
                bool better = (kbest < 0) || (dex < dbest) || (dex == dbest && k < kbest);
                if (better) { dbest = dex; kbest = k; }
            }
            if (l == 0) s_amin[px] = kbest;
        }
    }
    __syncthreads();

    // q gather (overwrites flat_n region for this block's pixels)
    int px2 = tid & 15, cs = tid >> 4;
#pragma unroll
    for (int it = 0; it < 24; ++it) {
        int c = cs + 16 * it;
        q_out[((size_t)(b * C_ + c)) * HW_ + hw0 + px2] = code_n[(size_t)s_amin[px2] * C_ + c];
    }
}

extern "C" void kernel_launch(void* const* d_in, const int* in_sizes, int n_in,
                              void* d_out, int out_size, void* d_ws, size_t ws_size,
                              hipStream_t stream) {
    const float* feat = (const float*)d_in[0];
    const float* cb   = (const float*)d_in[1];
    float* out    = (float*)d_out;
    float* f_out  = out + OFF_F;
    float* q_out  = out + OFF_Q;     // also holds flat_n (fp32, CHW) until K4's final phase
    float* asg    = out + OFF_ASG;   // first 20.8 MB holds a_hi/b_hi until K4 rewrites
    float* dist   = out + OFF_DIST;
    float* code_n = (float*)d_ws;    // 3.1 MB
    u16*   a_hi   = (u16*)asg;
    u16*   b_hi   = a_hi + (size_t)N_ * C_;
    float* flatn  = q_out;

    k_code<<<K_ / 4, 256, 0, stream>>>(cb, code_n, b_hi);
    k_prep<<<dim3(HW_ / 16, B_), 256, 0, stream>>>(feat, f_out, flatn, a_hi);
    k_gemm<<<dim3(K_ / 128, N_ / 128), 256, 0, stream>>>(a_hi, b_hi, dist);
    k_post<<<N_ / 16, 256, 0, stream>>>(dist, code_n, flatn, asg, q_out);
}